// Round 3
// baseline (2391.224 us; speedup 1.0000x reference)
//
#include <hip/hip_runtime.h>
#include <math.h>

// ---------------------------------------------------------------------------
// SNN forward (snntorch LIF, reset-by-subtraction) — R3: numpy-fp32 bit emu.
//
// R2 post-mortem: fp32 and fp64 kernels gave BIT-IDENTICAL absmax 6.64e-2 =
// 17*2^-8  =>  (a) dynamics robust to my internal precision (no chaos at my
// noise scale), (b) arbiter is NOT fp64 (exact fp64 didn't match), (c) the
// comparison is bf16-quantized (error an exact multiple of 2^-8). Conclusion:
// the np arbiter is float32; the few flipped spikes come from accumulation-
// ORDER differences vs numpy's BLAS sgemm.  Fix: bit-emulate numpy fp32:
//   - dot products: single accumulator, strictly sequential fmaf over k
//     ascending, seeded 0.0f, bias added once at the end (__fadd_rn)
//   - LIF update: individually-rounded ops, NO fma contraction:
//     m = __fsub_rn(__fadd_rn(__fmul_rn(B,m), cur), reset*thr)
//   - spike: __fsub_rn(m, thr) > 0
// Structure unchanged: 256 blocks x 512 thr, 2 groups x 256 neurons, 2 batch
// rows/group, whole T loop in-kernel, weights packed [C/4][R][4].
// ---------------------------------------------------------------------------

namespace {

constexpr int Bsz = 1024;
constexpr int Dd  = 256;
constexpr int Tt  = 128;
constexpr int Hh  = 256;
constexpr int Oo  = 64;
constexpr int G   = 4;   // batch rows per block
constexpr int TS  = 8;   // timesteps staged in LDS (44 KiB static LDS)

__global__ void pack_w(const float* __restrict__ W, float* __restrict__ Wp,
                       int R, int C) {
    int idx = blockIdx.x * 256 + threadIdx.x;
    if (idx >= R * C) return;
    int r = idx / C, c = idx % C;
    Wp[(size_t)((c >> 2) * R + r) * 4 + (c & 3)] = W[idx];
}

__device__ __forceinline__ float clamp01(float v) {
    return fminf(fmaxf(v, 0.f), 1.f);
}

// numpy-exact LIF state update + spike (all ops individually rounded fp32)
__device__ __forceinline__ float lif_update(float& m, float cur, float B, float Th) {
    const float reset = (__fsub_rn(m, Th) > 0.f) ? Th : 0.f;  // reset*thr exact
    m = __fsub_rn(__fadd_rn(__fmul_rn(B, m), cur), reset);
    return (__fsub_rn(m, Th) > 0.f) ? 1.f : 0.f;
}

__global__ __launch_bounds__(512) void snn_npemu(
    const float* __restrict__ x,
    const float* __restrict__ Wp_in,
    const float* __restrict__ Wp_h,
    const float* __restrict__ Wp_h1,
    const float* __restrict__ Wp_f,
    const float* __restrict__ Wp_a,
    const float* __restrict__ b_in, const float* __restrict__ beta1, const float* __restrict__ thr1,
    const float* __restrict__ b_h,  const float* __restrict__ beta2, const float* __restrict__ thr2,
    const float* __restrict__ b_h1,
    const float* __restrict__ b_f,  const float* __restrict__ beta_f,
    const float* __restrict__ b_a,  const float* __restrict__ beta_a,
    float* __restrict__ out)
{
    __shared__ float xs[TS][G][Dd];   // 32 KiB
    __shared__ float sp[3][G][Hh];    // 12 KiB

    const int tid = threadIdx.x;
    const int grp = tid >> 8;
    const int h   = tid & 255;
    const int b0  = blockIdx.x * G;
    const int g0  = grp * 2;

    float m1[2] = {0.f, 0.f};
    float m2[2] = {0.f, 0.f};
    float m3[2] = {0.f, 0.f};
    float mo[2] = {0.f, 0.f};

    const float bin = b_in[h];
    const float B1  = clamp01(beta1[h]);
    const float Th1 = thr1[h];
    const float bh  = b_h[h];
    const float B2  = clamp01(beta2[h]);
    const float Th2 = thr2[h];
    const float bh1 = b_h1[h];

    const int o = h & 63;
    float bo = 0.f, Bo = 0.f;
    if (h < 64)       { bo = b_f[o]; Bo = clamp01(beta_f[o]); }
    else if (h < 128) { bo = b_a[o]; Bo = clamp01(beta_a[o]); }
    const float* __restrict__ Wp_o = (h < 64) ? Wp_f : Wp_a;

    for (int t0 = 0; t0 < Tt; t0 += TS) {
        __syncthreads();
        #pragma unroll
        for (int k = 0; k < 2; ++k) {
            const int p = tid + k * 512;
            const int g = p >> 8;
            const int d = p & 255;
            const float* xp = x + ((size_t)(b0 + g) * Dd + d) * Tt + t0;
            const float4 v0 = *(const float4*)xp;
            const float4 v1 = *(const float4*)(xp + 4);
            xs[0][g][d] = v0.x; xs[1][g][d] = v0.y;
            xs[2][g][d] = v0.z; xs[3][g][d] = v0.w;
            xs[4][g][d] = v1.x; xs[5][g][d] = v1.y;
            xs[6][g][d] = v1.z; xs[7][g][d] = v1.w;
        }
        __syncthreads();

        for (int ts = 0; ts < TS; ++ts) {
            // ---- layer 1: cur1 = x_t @ W_in^T, sequential fmaf, +bias at end
            float c0 = 0.f, c1 = 0.f;
            #pragma unroll 4
            for (int d4 = 0; d4 < Dd / 4; ++d4) {
                const float4 w  = *(const float4*)(Wp_in + (size_t)(d4 * Hh + h) * 4);
                const float4 a0 = *(const float4*)&xs[ts][g0 + 0][d4 * 4];
                const float4 a1 = *(const float4*)&xs[ts][g0 + 1][d4 * 4];
                c0 = fmaf(a0.x, w.x, c0); c1 = fmaf(a1.x, w.x, c1);
                c0 = fmaf(a0.y, w.y, c0); c1 = fmaf(a1.y, w.y, c1);
                c0 = fmaf(a0.z, w.z, c0); c1 = fmaf(a1.z, w.z, c1);
                c0 = fmaf(a0.w, w.w, c0); c1 = fmaf(a1.w, w.w, c1);
            }
            c0 = __fadd_rn(c0, bin);
            c1 = __fadd_rn(c1, bin);
            sp[0][g0 + 0][h] = lif_update(m1[0], c0, B1, Th1);
            sp[0][g0 + 1][h] = lif_update(m1[1], c1, B1, Th1);
            __syncthreads();

            // ---- layer 2: cur2 = s1 @ W_h^T + b_h -------------------------
            c0 = 0.f; c1 = 0.f;
            #pragma unroll 4
            for (int d4 = 0; d4 < Hh / 4; ++d4) {
                const float4 w  = *(const float4*)(Wp_h + (size_t)(d4 * Hh + h) * 4);
                const float4 a0 = *(const float4*)&sp[0][g0 + 0][d4 * 4];
                const float4 a1 = *(const float4*)&sp[0][g0 + 1][d4 * 4];
                c0 = fmaf(a0.x, w.x, c0); c1 = fmaf(a1.x, w.x, c1);
                c0 = fmaf(a0.y, w.y, c0); c1 = fmaf(a1.y, w.y, c1);
                c0 = fmaf(a0.z, w.z, c0); c1 = fmaf(a1.z, w.z, c1);
                c0 = fmaf(a0.w, w.w, c0); c1 = fmaf(a1.w, w.w, c1);
            }
            c0 = __fadd_rn(c0, bh);
            c1 = __fadd_rn(c1, bh);
            sp[1][g0 + 0][h] = lif_update(m2[0], c0, B2, Th2);
            sp[1][g0 + 1][h] = lif_update(m2[1], c1, B2, Th2);
            __syncthreads();

            // ---- layer 3: cur3 = s2 @ W_h1^T + b_h1 (beta2/thr2 reuse bug) -
            c0 = 0.f; c1 = 0.f;
            #pragma unroll 4
            for (int d4 = 0; d4 < Hh / 4; ++d4) {
                const float4 w  = *(const float4*)(Wp_h1 + (size_t)(d4 * Hh + h) * 4);
                const float4 a0 = *(const float4*)&sp[1][g0 + 0][d4 * 4];
                const float4 a1 = *(const float4*)&sp[1][g0 + 1][d4 * 4];
                c0 = fmaf(a0.x, w.x, c0); c1 = fmaf(a1.x, w.x, c1);
                c0 = fmaf(a0.y, w.y, c0); c1 = fmaf(a1.y, w.y, c1);
                c0 = fmaf(a0.z, w.z, c0); c1 = fmaf(a1.z, w.z, c1);
                c0 = fmaf(a0.w, w.w, c0); c1 = fmaf(a1.w, w.w, c1);
            }
            c0 = __fadd_rn(c0, bh1);
            c1 = __fadd_rn(c1, bh1);
            sp[2][g0 + 0][h] = lif_update(m3[0], c0, B2, Th2);
            sp[2][g0 + 1][h] = lif_update(m3[1], c1, B2, Th2);
            __syncthreads();

            // ---- output LI neurons: m = fl(fl(B*m) + fl(dot + b)) ---------
            if (h < 128) {
                float co0 = 0.f, co1 = 0.f;
                #pragma unroll 4
                for (int d4 = 0; d4 < Hh / 4; ++d4) {
                    const float4 w  = *(const float4*)(Wp_o + (size_t)(d4 * Oo + o) * 4);
                    const float4 a0 = *(const float4*)&sp[2][g0 + 0][d4 * 4];
                    const float4 a1 = *(const float4*)&sp[2][g0 + 1][d4 * 4];
                    co0 = fmaf(a0.x, w.x, co0); co1 = fmaf(a1.x, w.x, co1);
                    co0 = fmaf(a0.y, w.y, co0); co1 = fmaf(a1.y, w.y, co1);
                    co0 = fmaf(a0.z, w.z, co0); co1 = fmaf(a1.z, w.z, co1);
                    co0 = fmaf(a0.w, w.w, co0); co1 = fmaf(a1.w, w.w, co1);
                }
                co0 = __fadd_rn(co0, bo);
                co1 = __fadd_rn(co1, bo);
                mo[0] = __fadd_rn(__fmul_rn(Bo, mo[0]), co0);
                mo[1] = __fadd_rn(__fmul_rn(Bo, mo[1]), co1);
            }
            // no barrier needed: next write to sp[2] is two barriers away
        }
    }

    if (h < 128) {
        float* dst = out + ((h < 64) ? 0 : (size_t)Bsz * Oo);
        dst[(size_t)(b0 + g0 + 0) * Oo + o] = (float)(1.0 / (1.0 + exp(-(double)mo[0])));
        dst[(size_t)(b0 + g0 + 1) * Oo + o] = (float)(1.0 / (1.0 + exp(-(double)mo[1])));
    }
}

} // namespace

extern "C" void kernel_launch(void* const* d_in, const int* in_sizes, int n_in,
                              void* d_out, int out_size, void* d_ws, size_t ws_size,
                              hipStream_t stream) {
    const float* x      = (const float*)d_in[0];
    const float* W_in   = (const float*)d_in[1];
    const float* b_in   = (const float*)d_in[2];
    const float* beta1  = (const float*)d_in[3];
    const float* thr1   = (const float*)d_in[4];
    const float* W_h    = (const float*)d_in[5];
    const float* b_h    = (const float*)d_in[6];
    const float* beta2  = (const float*)d_in[7];
    const float* thr2   = (const float*)d_in[8];
    const float* W_h1   = (const float*)d_in[9];
    const float* b_h1   = (const float*)d_in[10];
    const float* W_f    = (const float*)d_in[11];
    const float* b_f    = (const float*)d_in[12];
    const float* beta_f = (const float*)d_in[13];
    const float* W_a    = (const float*)d_in[14];
    const float* b_a    = (const float*)d_in[15];
    const float* beta_a = (const float*)d_in[16];
    float* out = (float*)d_out;

    float* ws    = (float*)d_ws;
    float* Wp_in = ws;                 // 65536 floats
    float* Wp_h  = ws + 65536;         // 65536
    float* Wp_h1 = ws + 131072;        // 65536
    float* Wp_f  = ws + 196608;        // 16384
    float* Wp_a  = ws + 212992;        // 16384  (total 917504 bytes)

    pack_w<<<(Hh * Dd + 255) / 256, 256, 0, stream>>>(W_in, Wp_in, Hh, Dd);
    pack_w<<<(Hh * Hh + 255) / 256, 256, 0, stream>>>(W_h,  Wp_h,  Hh, Hh);
    pack_w<<<(Hh * Hh + 255) / 256, 256, 0, stream>>>(W_h1, Wp_h1, Hh, Hh);
    pack_w<<<(Oo * Hh + 255) / 256, 256, 0, stream>>>(W_f,  Wp_f,  Oo, Hh);
    pack_w<<<(Oo * Hh + 255) / 256, 256, 0, stream>>>(W_a,  Wp_a,  Oo, Hh);

    snn_npemu<<<Bsz / G, 512, 0, stream>>>(
        x, Wp_in, Wp_h, Wp_h1, Wp_f, Wp_a,
        b_in, beta1, thr1, b_h, beta2, thr2, b_h1,
        b_f, beta_f, b_a, beta_a, out);
}

// Round 4
// 2011.417 us; speedup vs baseline: 1.1888x; 1.1888x over previous
//
#include <hip/hip_runtime.h>
#include <math.h>
#include <stdint.h>

// ---------------------------------------------------------------------------
// SNN forward — R4: layer-1 GEMM hoist + spike-driven sparse recurrence.
//
// R3 passed (absmax 4.88e-4) with numpy-fp32 bit emulation: sequential-k fmaf
// chains seeded 0, bias __fadd_rn at end, individually-rounded LIF ops.
// R3 counters: VALUBusy 54%, occupancy 23.7% (grid 256 = 1 block/CU),
// latency/barrier-bound; weights re-streamed from L2 every timestep.
//
// R4 (bit-exact-preserving transforms only):
//  1. cur1 = x@W_in^T + b_in hoisted to a chunked GEMM (same fmaf order),
//     staged in d_ws; removes 1/3 of the serial path.
//  2. Layers 2/3/out consume spikes as bitmask index lists: skipped k adds
//     exactly 0 in numpy (fmaf(0,w,c)==c); taken k is __fadd_rn(c,w) ==
//     fmaf(1,w,c). Lists ascending-k, sentinel-padded to a ZERO weight row
//     (k=256) so fadd(c,0)=c exactly (c never -0: starts +0, RN sums).
//  3. Grid 512 (2 blocks/CU) — sparse traffic makes this affordable.
// ---------------------------------------------------------------------------

namespace {

constexpr int Bsz = 1024;
constexpr int Dd  = 256;
constexpr int Tt  = 128;
constexpr int Hh  = 256;
constexpr int Oo  = 64;

// Wt[c*R + r] = W[r*C + c] for c<C; row c==C zeroed (sparse sentinel target).
__global__ void pack_t(const float* __restrict__ W, float* __restrict__ Wt,
                       int R, int C) {
    int idx = blockIdx.x * 256 + threadIdx.x;
    if (idx >= (C + 1) * R) return;
    int c = idx / R, r = idx - c * R;
    Wt[idx] = (c < C) ? W[(size_t)r * C + c] : 0.f;
}

__device__ __forceinline__ float clamp01(float v) {
    return fminf(fmaxf(v, 0.f), 1.f);
}

// ---------------- layer-1 GEMM: cur1[tl,b,h] = sum_d x[b,d,t]*W_in[h,d] + b_in[h]
// Sequential-d fmaf chain per element (bit-identical to R3's inline layer 1).
template<int TT>
__global__ __launch_bounds__(256) void gemm_l1(
    const float* __restrict__ x, const float* __restrict__ Wt_in,
    const float* __restrict__ b_in, float* __restrict__ cur1, int tg_base)
{
    const int h  = threadIdx.x;
    const int b  = blockIdx.x;
    const int tt = blockIdx.y;
    const int tg0 = tg_base + tt * TT;   // global t of first column
    float c[TT];
    #pragma unroll
    for (int j = 0; j < TT; ++j) c[j] = 0.f;
    const float* xb = x + (size_t)b * Dd * Tt + tg0;
    for (int d = 0; d < Dd; ++d) {
        const float w = Wt_in[d * Hh + h];          // coalesced over h
        const float* xp = xb + (size_t)d * Tt;      // uniform -> s_load
        #pragma unroll
        for (int j = 0; j < TT; ++j) c[j] = fmaf(w, xp[j], c[j]);
    }
    const float bb = b_in[h];
    const int tl0 = tt * TT;
    #pragma unroll
    for (int j = 0; j < TT; ++j)
        cur1[((size_t)(tl0 + j) * Bsz + b) * Hh + h] = __fadd_rn(c[j], bb);
}

// ---------------- recurrent kernel helpers ---------------------------------

__device__ __forceinline__ bool lif_step(float& m, float cur, float B, float Th) {
    const float r = (__fsub_rn(m, Th) > 0.f) ? Th : 0.f;   // reset from PREVIOUS mem
    m = __fsub_rn(__fadd_rn(__fmul_rn(B, m), cur), r);
    return __fsub_rn(m, Th) > 0.f;
}

__device__ __forceinline__ uint64_t rfl64(uint64_t v) {
    uint32_t lo = __builtin_amdgcn_readfirstlane((uint32_t)v);
    uint32_t hi = __builtin_amdgcn_readfirstlane((uint32_t)(v >> 32));
    return ((uint64_t)hi << 32) | lo;
}

// Build ascending-k index lists for two rows from spike predicates.
// Returns common padded length (uniform). Sentinel index = Hh (zero row).
__device__ __forceinline__ int build_lists(bool pA, bool pB, int tid,
    uint64_t* smask, uint32_t* idx0, uint32_t* idx1)
{
    const int wid = tid >> 6, lane = tid & 63;
    const uint64_t bmA = __ballot(pA);
    const uint64_t bmB = __ballot(pB);
    if (lane == 0) { smask[wid] = bmA; smask[4 + wid] = bmB; }
    __syncthreads();
    uint64_t mA[4], mB[4];
    #pragma unroll
    for (int w = 0; w < 4; ++w) { mA[w] = rfl64(smask[w]); mB[w] = rfl64(smask[4 + w]); }
    int nA = 0, nB = 0, bA[4], bB[4];
    #pragma unroll
    for (int w = 0; w < 4; ++w) {
        bA[w] = nA; nA += __popcll(mA[w]);
        bB[w] = nB; nB += __popcll(mB[w]);
    }
    const uint64_t low = (lane == 0) ? 0ull : (~0ull >> (64 - lane));
    { uint64_t m = mA[wid]; if ((m >> lane) & 1ull) idx0[bA[wid] + __popcll(m & low)] = (uint32_t)tid; }
    { uint64_t m = mB[wid]; if ((m >> lane) & 1ull) idx1[bB[wid] + __popcll(m & low)] = (uint32_t)tid; }
    const int n = nA > nB ? nA : nB;
    const int npad = (n + 3) & ~3;
    for (int j = nA + tid; j < npad; j += 256) idx0[j] = (uint32_t)Hh;
    for (int j = nB + tid; j < npad; j += 256) idx1[j] = (uint32_t)Hh;
    __syncthreads();
    return npad;
}

// Sparse accumulate: ascending-k __fadd_rn chains for two rows, unroll 4,
// 8 independent weight loads in flight per group.
__device__ __forceinline__ void sparse_acc(const uint32_t* idx0, const uint32_t* idx1,
    int npad, const float* __restrict__ tab, int shift, uint32_t eb,
    float& o0, float& o1)
{
    float a0 = 0.f, a1 = 0.f;
    const char* tb = (const char*)tab;
    for (int i = 0; i < npad; i += 4) {
        const uint4 kA = *(const uint4*)(idx0 + i);
        const uint4 kB = *(const uint4*)(idx1 + i);
        const float wA0 = *(const float*)(tb + ((kA.x << shift) | eb));
        const float wA1 = *(const float*)(tb + ((kA.y << shift) | eb));
        const float wA2 = *(const float*)(tb + ((kA.z << shift) | eb));
        const float wA3 = *(const float*)(tb + ((kA.w << shift) | eb));
        const float wB0 = *(const float*)(tb + ((kB.x << shift) | eb));
        const float wB1 = *(const float*)(tb + ((kB.y << shift) | eb));
        const float wB2 = *(const float*)(tb + ((kB.z << shift) | eb));
        const float wB3 = *(const float*)(tb + ((kB.w << shift) | eb));
        a0 = __fadd_rn(a0, wA0); a0 = __fadd_rn(a0, wA1);
        a0 = __fadd_rn(a0, wA2); a0 = __fadd_rn(a0, wA3);
        a1 = __fadd_rn(a1, wB0); a1 = __fadd_rn(a1, wB1);
        a1 = __fadd_rn(a1, wB2); a1 = __fadd_rn(a1, wB3);
    }
    o0 = a0; o1 = a1;
}

// ---------------- recurrent kernel: layers 2,3,out over one T-chunk --------
// 512 blocks x 256 threads (h), 2 batch rows per block.
__global__ __launch_bounds__(256) void snn_rec(
    const float* __restrict__ cur1,
    const float* __restrict__ Wt_h, const float* __restrict__ Wt_h1,
    const float* __restrict__ Wt_f, const float* __restrict__ Wt_a,
    const float* __restrict__ beta1, const float* __restrict__ thr1,
    const float* __restrict__ b_h,  const float* __restrict__ beta2, const float* __restrict__ thr2,
    const float* __restrict__ b_h1,
    const float* __restrict__ b_f,  const float* __restrict__ beta_f,
    const float* __restrict__ b_a,  const float* __restrict__ beta_a,
    float* __restrict__ m1s, float* __restrict__ m2s, float* __restrict__ m3s,
    float* __restrict__ mos, float* __restrict__ out,
    int TC, int first)
{
    __shared__ uint64_t smask[8];
    __shared__ __attribute__((aligned(16))) uint32_t idx0[256];
    __shared__ __attribute__((aligned(16))) uint32_t idx1[256];

    const int tid = threadIdx.x;
    const int h   = tid;
    const int b0  = blockIdx.x * 2;

    const float B1  = clamp01(beta1[h]), Th1 = thr1[h];
    const float bh  = b_h[h];
    const float B2  = clamp01(beta2[h]), Th2 = thr2[h];
    const float bh1 = b_h1[h];
    const int o   = h & 63;
    const int sel = (h >> 6) & 1;                    // wave-uniform f/a select
    const float bo = sel ? b_a[o] : b_f[o];
    const float Bo = clamp01(sel ? beta_a[o] : beta_f[o]);
    const float* tabO = sel ? Wt_a : Wt_f;

    float m1A, m1B, m2A, m2B, m3A, m3B, moA, moB;
    if (first) {
        m1A = m1B = m2A = m2B = m3A = m3B = moA = moB = 0.f;
    } else {
        m1A = m1s[(b0 + 0) * Hh + h]; m1B = m1s[(b0 + 1) * Hh + h];
        m2A = m2s[(b0 + 0) * Hh + h]; m2B = m2s[(b0 + 1) * Hh + h];
        m3A = m3s[(b0 + 0) * Hh + h]; m3B = m3s[(b0 + 1) * Hh + h];
        if (h < 128) { moA = mos[(b0 + 0) * 128 + h]; moB = mos[(b0 + 1) * 128 + h]; }
        else         { moA = moB = 0.f; }
    }
    const uint32_t eb  = (uint32_t)(h << 2);
    const uint32_t ebo = (uint32_t)(o << 2);

    for (int t = 0; t < TC; ++t) {
        const float cA = cur1[((size_t)t * Bsz + b0    ) * Hh + h];
        const float cB = cur1[((size_t)t * Bsz + b0 + 1) * Hh + h];
        bool pA = lif_step(m1A, cA, B1, Th1);
        bool pB = lif_step(m1B, cB, B1, Th1);
        int npad = build_lists(pA, pB, tid, smask, idx0, idx1);
        float s0, s1v;
        sparse_acc(idx0, idx1, npad, Wt_h, 10, eb, s0, s1v);
        pA = lif_step(m2A, __fadd_rn(s0,  bh), B2, Th2);
        pB = lif_step(m2B, __fadd_rn(s1v, bh), B2, Th2);
        npad = build_lists(pA, pB, tid, smask, idx0, idx1);
        sparse_acc(idx0, idx1, npad, Wt_h1, 10, eb, s0, s1v);
        pA = lif_step(m3A, __fadd_rn(s0,  bh1), B2, Th2);   // layer-3 reuses beta2/thr2
        pB = lif_step(m3B, __fadd_rn(s1v, bh1), B2, Th2);
        npad = build_lists(pA, pB, tid, smask, idx0, idx1);
        sparse_acc(idx0, idx1, npad, tabO, 8, ebo, s0, s1v);
        moA = __fadd_rn(__fmul_rn(Bo, moA), __fadd_rn(s0,  bo));
        moB = __fadd_rn(__fmul_rn(Bo, moB), __fadd_rn(s1v, bo));
    }

    m1s[(b0 + 0) * Hh + h] = m1A; m1s[(b0 + 1) * Hh + h] = m1B;
    m2s[(b0 + 0) * Hh + h] = m2A; m2s[(b0 + 1) * Hh + h] = m2B;
    m3s[(b0 + 0) * Hh + h] = m3A; m3s[(b0 + 1) * Hh + h] = m3B;
    if (h < 128) {
        mos[(b0 + 0) * 128 + h] = moA; mos[(b0 + 1) * 128 + h] = moB;
        float* dst = out + (sel ? (size_t)Bsz * Oo : 0);
        dst[(size_t)(b0 + 0) * Oo + o] = (float)(1.0 / (1.0 + exp(-(double)moA)));
        dst[(size_t)(b0 + 1) * Oo + o] = (float)(1.0 / (1.0 + exp(-(double)moB)));
    }
}

} // namespace

extern "C" void kernel_launch(void* const* d_in, const int* in_sizes, int n_in,
                              void* d_out, int out_size, void* d_ws, size_t ws_size,
                              hipStream_t stream) {
    const float* x      = (const float*)d_in[0];
    const float* W_in   = (const float*)d_in[1];
    const float* b_in   = (const float*)d_in[2];
    const float* beta1  = (const float*)d_in[3];
    const float* thr1   = (const float*)d_in[4];
    const float* W_h    = (const float*)d_in[5];
    const float* b_h    = (const float*)d_in[6];
    const float* beta2  = (const float*)d_in[7];
    const float* thr2   = (const float*)d_in[8];
    const float* W_h1   = (const float*)d_in[9];
    const float* b_h1   = (const float*)d_in[10];
    const float* W_f    = (const float*)d_in[11];
    const float* b_f    = (const float*)d_in[12];
    const float* beta_f = (const float*)d_in[13];
    const float* W_a    = (const float*)d_in[14];
    const float* b_a    = (const float*)d_in[15];
    const float* beta_a = (const float*)d_in[16];
    float* out = (float*)d_out;

    float* ws = (float*)d_ws;
    size_t off = 0;
    auto alloc = [&](size_t n) { float* p = ws + off; off += n; return p; };
    float* Wt_in = alloc(257 * 256);
    float* Wt_h  = alloc(257 * 256);
    float* Wt_h1 = alloc(257 * 256);
    float* Wt_f  = alloc(257 * 64);
    float* Wt_a  = alloc(257 * 64);
    float* m1s   = alloc((size_t)Bsz * Hh);
    float* m2s   = alloc((size_t)Bsz * Hh);
    float* m3s   = alloc((size_t)Bsz * Hh);
    float* mos   = alloc((size_t)Bsz * 128);
    const size_t fixed = off;

    int TC = 1;
    const int cands[6] = {32, 16, 8, 4, 2, 1};
    for (int i = 0; i < 6; ++i) {
        if ((fixed + (size_t)cands[i] * Bsz * Hh) * sizeof(float) <= ws_size) { TC = cands[i]; break; }
    }
    float* cur1 = alloc((size_t)TC * Bsz * Hh);

    pack_t<<<257, 256, 0, stream>>>(W_in, Wt_in, 256, 256);
    pack_t<<<257, 256, 0, stream>>>(W_h,  Wt_h,  256, 256);
    pack_t<<<257, 256, 0, stream>>>(W_h1, Wt_h1, 256, 256);
    pack_t<<<65,  256, 0, stream>>>(W_f,  Wt_f,  64, 256);
    pack_t<<<65,  256, 0, stream>>>(W_a,  Wt_a,  64, 256);

    const int nch = Tt / TC;
    for (int c = 0; c < nch; ++c) {
        const int tg = c * TC;
        if (TC >= 8)
            gemm_l1<8><<<dim3(Bsz, TC / 8), 256, 0, stream>>>(x, Wt_in, b_in, cur1, tg);
        else if (TC == 4)
            gemm_l1<4><<<dim3(Bsz, 1), 256, 0, stream>>>(x, Wt_in, b_in, cur1, tg);
        else if (TC == 2)
            gemm_l1<2><<<dim3(Bsz, 1), 256, 0, stream>>>(x, Wt_in, b_in, cur1, tg);
        else
            gemm_l1<1><<<dim3(Bsz, 1), 256, 0, stream>>>(x, Wt_in, b_in, cur1, tg);

        snn_rec<<<Bsz / 2, 256, 0, stream>>>(
            cur1, Wt_h, Wt_h1, Wt_f, Wt_a,
            beta1, thr1, b_h, beta2, thr2, b_h1,
            b_f, beta_f, b_a, beta_a,
            m1s, m2s, m3s, mos, out, TC, (c == 0) ? 1 : 0);
    }
}